// Round 1
// baseline (320.192 us; speedup 1.0000x reference)
//
#include <hip/hip_runtime.h>

// Problem constants (from reference setup_inputs)
constexpr int Bb = 32;      // batch
constexpr int Mm = 65536;   // memory slots
constexpr int Ww = 32;      // word width
constexpr int Rr = 4;       // read heads
constexpr int Dd = 256;     // d_in
constexpr int Kk = 8;       // K_NEIGHBORS

constexpr int NB_A = 64;            // blocks per batch, phase A
constexpr int TPB_A = 256;          // threads per block, phase A
constexpr int ROWS_PER_BLOCK = Mm / NB_A;          // 1024
constexpr int QQ = ROWS_PER_BLOCK / TPB_A;         // 4 rows per thread

// ---------------------------------------------------------------------------
// Kernel 1: read_keys = xi @ W_rk^T + b_rk  (32 x 128), plus ||rk||^2 per (b,r)
// ---------------------------------------------------------------------------
__global__ __launch_bounds__(128) void rk_kernel(
    const float* __restrict__ xi, const float* __restrict__ Wrk,
    const float* __restrict__ brk, float* __restrict__ rk,
    float* __restrict__ rknorm) {
  const int b = blockIdx.x;
  const int tid = threadIdx.x;  // 128 threads = one rw each
  __shared__ float xs[Dd];
  __shared__ float rks[Rr * Ww];
  #pragma unroll
  for (int i = 0; i < Dd; i += 128) xs[i + tid] = xi[b * Dd + i + tid];
  __syncthreads();
  float acc = brk[tid];
  const float4* wr = reinterpret_cast<const float4*>(Wrk + (size_t)tid * Dd);
  #pragma unroll 4
  for (int i = 0; i < Dd / 4; ++i) {
    float4 wv = wr[i];
    acc = fmaf(wv.x, xs[4 * i + 0], acc);
    acc = fmaf(wv.y, xs[4 * i + 1], acc);
    acc = fmaf(wv.z, xs[4 * i + 2], acc);
    acc = fmaf(wv.w, xs[4 * i + 3], acc);
  }
  rk[b * Rr * Ww + tid] = acc;
  rks[tid] = acc;
  __syncthreads();
  if (tid < Rr) {
    float s = 0.f;
    #pragma unroll
    for (int j = 0; j < Ww; ++j) s = fmaf(rks[tid * Ww + j], rks[tid * Ww + j], s);
    rknorm[b * Rr + tid] = s;
  }
}

// ---------------------------------------------------------------------------
// Kernel 2: stream sparse[b], compute d2 for 4 read-heads, per-block top-8
// ---------------------------------------------------------------------------
__global__ __launch_bounds__(TPB_A, 4) void topk_partial(
    const float* __restrict__ sparse, const float* __restrict__ rk,
    const float* __restrict__ rknorm, float* __restrict__ cand_d,
    int* __restrict__ cand_i) {
  const int b = blockIdx.y;
  const int tid = threadIdx.x;
  __shared__ float rk_s[Rr][Ww];
  __shared__ float rkn_s[Rr];
  if (tid < Rr * Ww) rk_s[tid >> 5][tid & 31] = rk[b * Rr * Ww + tid];
  if (tid < Rr) rkn_s[tid] = rknorm[b * Rr + tid];
  __syncthreads();

  const int m0 = blockIdx.x * ROWS_PER_BLOCK;
  const float* sb = sparse + (size_t)b * Mm * Ww;

  // --- streaming pass: 4 rows per thread (coalesced: consecutive lanes =
  // consecutive rows), rk fragments from LDS as float4 broadcast reads ---
  float dot[QQ][Rr];
  float ss[QQ];
  const float4* rowp[QQ];
  #pragma unroll
  for (int q = 0; q < QQ; ++q) {
    ss[q] = 0.f;
    #pragma unroll
    for (int r = 0; r < Rr; ++r) dot[q][r] = 0.f;
    rowp[q] = reinterpret_cast<const float4*>(sb + (size_t)(m0 + q * TPB_A + tid) * Ww);
  }
  #pragma unroll
  for (int j = 0; j < Ww / 4; ++j) {
    float4 v[QQ];
    #pragma unroll
    for (int q = 0; q < QQ; ++q) v[q] = rowp[q][j];
    #pragma unroll
    for (int r = 0; r < Rr; ++r) {
      float4 rkv = *reinterpret_cast<const float4*>(&rk_s[r][4 * j]);
      #pragma unroll
      for (int q = 0; q < QQ; ++q) {
        dot[q][r] = fmaf(rkv.x, v[q].x, dot[q][r]);
        dot[q][r] = fmaf(rkv.y, v[q].y, dot[q][r]);
        dot[q][r] = fmaf(rkv.z, v[q].z, dot[q][r]);
        dot[q][r] = fmaf(rkv.w, v[q].w, dot[q][r]);
      }
    }
    #pragma unroll
    for (int q = 0; q < QQ; ++q) {
      ss[q] = fmaf(v[q].x, v[q].x, ss[q]);
      ss[q] = fmaf(v[q].y, v[q].y, ss[q]);
      ss[q] = fmaf(v[q].z, v[q].z, ss[q]);
      ss[q] = fmaf(v[q].w, v[q].w, ss[q]);
    }
  }

  // per-thread candidate lists (static-indexed registers only)
  float d8[Rr][QQ];
  int i8[Rr][QQ];
  #pragma unroll
  for (int r = 0; r < Rr; ++r)
    #pragma unroll
    for (int q = 0; q < QQ; ++q) {
      d8[r][q] = rkn_s[r] - 2.f * dot[q][r] + ss[q];
      i8[r][q] = m0 + q * TPB_A + tid;
    }
  // sort each 4-list ascending (static bubble network)
  #pragma unroll
  for (int r = 0; r < Rr; ++r)
    #pragma unroll
    for (int i = 0; i < QQ - 1; ++i)
      #pragma unroll
      for (int j = 0; j < QQ - 1 - i; ++j)
        if (d8[r][j + 1] < d8[r][j] ||
            (d8[r][j + 1] == d8[r][j] && i8[r][j + 1] < i8[r][j])) {
          float td = d8[r][j]; d8[r][j] = d8[r][j + 1]; d8[r][j + 1] = td;
          int ti = i8[r][j]; i8[r][j] = i8[r][j + 1]; i8[r][j + 1] = ti;
        }

  // --- block-level top-8 per r via 8 rounds of argmin extraction ---
  __shared__ float sv[TPB_A / 64];
  __shared__ int si[TPB_A / 64];
  const int lane = tid & 63;
  const int wid = tid >> 6;
  const float INF = __builtin_inff();
  #pragma unroll
  for (int r = 0; r < Rr; ++r) {
    #pragma unroll
    for (int k = 0; k < Kk; ++k) {
      float v = d8[r][0];
      int id = i8[r][0];
      #pragma unroll
      for (int off = 32; off; off >>= 1) {
        float ov = __shfl_xor(v, off);
        int oi = __shfl_xor(id, off);
        if (ov < v || (ov == v && oi < id)) { v = ov; id = oi; }
      }
      if (lane == 0) { sv[wid] = v; si[wid] = id; }
      __syncthreads();
      float bv = sv[0]; int bi = si[0];
      #pragma unroll
      for (int u = 1; u < TPB_A / 64; ++u)
        if (sv[u] < bv || (sv[u] == bv && si[u] < bi)) { bv = sv[u]; bi = si[u]; }
      if (tid == 0) {
        size_t o = ((size_t)(b * Rr + r) * NB_A + blockIdx.x) * Kk + k;
        cand_d[o] = bv;
        cand_i[o] = bi;
      }
      __syncthreads();  // protect sv/si before next round's write
      if (i8[r][0] == bi) {  // unique owner pops its head
        #pragma unroll
        for (int j = 0; j < QQ - 1; ++j) { d8[r][j] = d8[r][j + 1]; i8[r][j] = i8[r][j + 1]; }
        d8[r][QQ - 1] = INF;
        i8[r][QQ - 1] = -1;
      }
    }
  }
}

// ---------------------------------------------------------------------------
// Kernel 3: merge 64*8 candidates per (b,r) -> global top-8, weights, gather
// ---------------------------------------------------------------------------
__global__ __launch_bounds__(64) void topk_final(
    const float* __restrict__ sparse, const float* __restrict__ cand_d,
    const int* __restrict__ cand_i, float* __restrict__ out) {
  const int br = blockIdx.x;  // b*4 + r
  const int b = br >> 2;
  const int r = br & 3;
  const int lane = threadIdx.x;  // 64
  const float INF = __builtin_inff();

  float ld[Kk];
  int li[Kk];
  const float* cd = cand_d + (size_t)br * (NB_A * Kk);
  const int* ci = cand_i + (size_t)br * (NB_A * Kk);
  #pragma unroll
  for (int t = 0; t < Kk; ++t) {
    ld[t] = cd[t * 64 + lane];
    li[t] = ci[t * 64 + lane];
  }
  // sort per-lane 8-list ascending (static bubble network)
  #pragma unroll
  for (int i = 0; i < Kk - 1; ++i)
    #pragma unroll
    for (int j = 0; j < Kk - 1 - i; ++j)
      if (ld[j + 1] < ld[j] || (ld[j + 1] == ld[j] && li[j + 1] < li[j])) {
        float td = ld[j]; ld[j] = ld[j + 1]; ld[j + 1] = td;
        int ti = li[j]; li[j] = li[j + 1]; li[j + 1] = ti;
      }

  __shared__ float s_td[Kk];
  __shared__ int s_ti[Kk];
  #pragma unroll
  for (int k = 0; k < Kk; ++k) {
    float v = ld[0];
    int id = li[0];
    #pragma unroll
    for (int off = 32; off; off >>= 1) {  // butterfly: all lanes get the min
      float ov = __shfl_xor(v, off);
      int oi = __shfl_xor(id, off);
      if (ov < v || (ov == v && oi < id)) { v = ov; id = oi; }
    }
    if (lane == 0) { s_td[k] = v; s_ti[k] = id; }
    if (li[0] == id) {  // owner pops head
      #pragma unroll
      for (int j = 0; j < Kk - 1; ++j) { ld[j] = ld[j + 1]; li[j] = li[j + 1]; }
      ld[Kk - 1] = INF;
      li[Kk - 1] = -1;
    }
  }
  __syncthreads();

  // read_weights[r][b][k] = dist_k / dist_7  (dist ascending -> max is last)
  const float dmax = s_td[Kk - 1];
  if (lane < Kk)
    out[(size_t)Rr * Bb * Kk * Ww + ((size_t)r * Bb + b) * Kk + lane] =
        s_td[lane] / dmax;

  // read_vectors[r][b][k][j] = sparse[b][idx_k][j]
  const float* sbase = sparse + (size_t)b * Mm * Ww;
  #pragma unroll
  for (int t = 0; t < (Kk * Ww) / 64; ++t) {
    int e = t * 64 + lane;
    int k = e >> 5;
    int j = e & 31;
    out[(((size_t)r * Bb + b) * Kk + k) * Ww + j] =
        sbase[(size_t)s_ti[k] * Ww + j];
  }
}

// ---------------------------------------------------------------------------
extern "C" void kernel_launch(void* const* d_in, const int* in_sizes, int n_in,
                              void* d_out, int out_size, void* d_ws,
                              size_t ws_size, hipStream_t stream) {
  const float* xi = (const float*)d_in[0];
  const float* sparse = (const float*)d_in[1];
  const float* Wrk = (const float*)d_in[2];
  const float* brk = (const float*)d_in[3];
  float* out = (float*)d_out;

  char* ws = (char*)d_ws;
  float* rk = (float*)ws;                          // 32*128*4      = 16384 B
  float* rknorm = (float*)(ws + 16384);            // 128*4         = 512 B
  float* cand_d = (float*)(ws + 16896);            // 32*4*64*8*4   = 262144 B
  int* cand_i = (int*)(ws + 16896 + 262144);       // 262144 B

  rk_kernel<<<Bb, 128, 0, stream>>>(xi, Wrk, brk, rk, rknorm);
  dim3 gridA(NB_A, Bb);
  topk_partial<<<gridA, TPB_A, 0, stream>>>(sparse, rk, rknorm, cand_d, cand_i);
  topk_final<<<Bb * Rr, 64, 0, stream>>>(sparse, cand_d, cand_i, out);
}